// Round 1
// baseline (363.870 us; speedup 1.0000x reference)
//
#include <hip/hip_runtime.h>
#include <hip/hip_bf16.h>
#include <stdint.h>

typedef __attribute__((ext_vector_type(8))) short bf16x8;
typedef __attribute__((ext_vector_type(4))) float f32x4;

#define MFMA16(a, b, c) __builtin_amdgcn_mfma_f32_16x16x32_bf16(a, b, c, 0, 0, 0)

constexpr float ATT_SCALE = 0.04419417382415922f; // 1/sqrt(512)

__device__ __forceinline__ void gload_lds16(const void* g, void* l) {
  __builtin_amdgcn_global_load_lds((const __attribute__((address_space(1))) uint32_t*)g,
                                   (__attribute__((address_space(3))) uint32_t*)l, 16, 0, 0);
}
__device__ __forceinline__ void gload_lds4(const void* g, void* l) {
  __builtin_amdgcn_global_load_lds((const __attribute__((address_space(1))) uint32_t*)g,
                                   (__attribute__((address_space(3))) uint32_t*)l, 4, 0, 0);
}
// read 8 bf16 (16B) at logical (row, 16B-chunk ch) of a row-major [R][64]bf16 tile,
// stored with source-side XOR swizzle: slot(row, c) holds element (row, c^(row&7))
__device__ __forceinline__ bf16x8 lds_read_swz(const short* base, int row, int ch) {
  return *(const bf16x8*)((const char*)base + row * 128 + (((ch ^ row) & 7) << 4));
}
__device__ __forceinline__ short f2b(float f) {
  __hip_bfloat16 h = __float2bfloat16(f);
  return *reinterpret_cast<short*>(&h);
}

// ---------------- converters ----------------
__global__ void k_cvt_x(const float* __restrict__ x, short* __restrict__ xb) {
  const int i = blockIdx.x * 256 + threadIdx.x;          // 1,048,576 threads, 4 elems each
  const float4 v = ((const float4*)x)[i];
  short4 o;
  o.x = f2b(v.x); o.y = f2b(v.y); o.z = f2b(v.z); o.w = f2b(v.w);
  ((short4*)xb)[i] = o;
}

// wt[mat][n][k] = bf16(W_mat[k][n]) ; mat: 0=Wq 1=Wk 2=Wv 3=Wo
__global__ void k_cvt_w(const float* __restrict__ wq, const float* __restrict__ wk,
                        const float* __restrict__ wv, const float* __restrict__ wo,
                        short* __restrict__ wt) {
  const int gid = blockIdx.x * 256 + threadIdx.x;        // 4*512*512 = 1,048,576
  const int mat = gid >> 18;
  const int idx = gid & 262143;
  const int n = idx >> 9, k = idx & 511;
  const float* w = (mat == 0) ? wq : (mat == 1) ? wk : (mat == 2) ? wv : wo;
  wt[gid] = f2b(w[k * 512 + n]);
}

// ---------------- GEMM: C[M x 64-block] = A[M x 512] * W^T-block + bias ----------------
// MODE 0: A = x_bf16, blockIdx.y in [0,24): mat=y>>3 (Q/K/V), head h=y&7.
//   Q -> qws[bh][s][d] * ATT_SCALE ; K -> kws[bh][s][d] ; V -> vws[bh][d][s] (transposed)
// MODE 1: A = attn_out bf16, W = Wo^T, f32 out[rows][512]
template <int MODE>
__global__ __launch_bounds__(256, 2) void k_gemm(
    const short* __restrict__ A, const short* __restrict__ W,
    const float* __restrict__ bias0, const float* __restrict__ bias1,
    const float* __restrict__ bias2,
    short* __restrict__ oq, short* __restrict__ ok, short* __restrict__ ov,
    float* __restrict__ fo) {
  __shared__ short Asm[2][128 * 64];
  __shared__ short Bsm[2][64 * 64];
  const int tid = threadIdx.x;
  const int wave = tid >> 6, lane = tid & 63;
  const int lane15 = lane & 15, g = lane >> 4;
  const int wm = wave >> 1, wn = wave & 1;
  const int m0 = blockIdx.x * 128;

  int mat = 0, n0, h = 0;
  const float* bptr;
  if constexpr (MODE == 0) {
    mat = blockIdx.y >> 3; h = blockIdx.y & 7; n0 = h * 64;
    bptr = (mat == 0) ? bias0 : (mat == 1) ? bias1 : bias2;
  } else {
    n0 = blockIdx.y * 64; bptr = bias0;
  }
  const char* Ag = (const char*)A + (size_t)m0 * 1024;
  const char* Bg = (const char*)(W + (size_t)mat * (512 * 512)) + (size_t)n0 * 1024;

  f32x4 acc[4][2] = {};

  auto stage = [&](int buf, int kt) {
    const int k0b = kt * 128;  // byte offset of K-slice within a 1024B row
#pragma unroll
    for (int q = 0; q < 4; ++q) {  // A tile: 128x64 bf16 = 16KB, 16 wave-calls
      int s_ = (wave * 4 + q) * 64 + lane;
      int row = s_ >> 3, ch = s_ & 7;
      gload_lds16(Ag + (size_t)row * 1024 + k0b + (((ch ^ row) & 7) << 4),
                  (char*)&Asm[buf][0] + s_ * 16);
    }
#pragma unroll
    for (int q = 0; q < 2; ++q) {  // B tile: 64x64 bf16 = 8KB
      int s_ = (wave * 2 + q) * 64 + lane;
      int row = s_ >> 3, ch = s_ & 7;
      gload_lds16(Bg + (size_t)row * 1024 + k0b + (((ch ^ row) & 7) << 4),
                  (char*)&Bsm[buf][0] + s_ * 16);
    }
  };

  stage(0, 0);
  asm volatile("s_waitcnt vmcnt(0)" ::: "memory");
  __syncthreads();

  for (int kt = 0; kt < 8; ++kt) {
    const int cur = kt & 1;
    if (kt < 7) stage(cur ^ 1, kt + 1);
#pragma unroll
    for (int kk = 0; kk < 2; ++kk) {
      bf16x8 af[4], bfr[2];
#pragma unroll
      for (int m = 0; m < 4; ++m)
        af[m] = lds_read_swz(&Asm[cur][0], wm * 64 + m * 16 + lane15, kk * 4 + g);
#pragma unroll
      for (int n = 0; n < 2; ++n)
        bfr[n] = lds_read_swz(&Bsm[cur][0], wn * 32 + n * 16 + lane15, kk * 4 + g);
#pragma unroll
      for (int m = 0; m < 4; ++m)
#pragma unroll
        for (int n = 0; n < 2; ++n)
          acc[m][n] = MFMA16(af[m], bfr[n], acc[m][n]);
    }
    asm volatile("s_waitcnt vmcnt(0)" ::: "memory");
    __syncthreads();
  }

#pragma unroll
  for (int n = 0; n < 2; ++n) {
    const int d = wn * 32 + n * 16 + lane15;  // col within the 64-wide block
    const float bias = bptr[n0 + d];
#pragma unroll
    for (int m = 0; m < 4; ++m) {
#pragma unroll
      for (int j = 0; j < 4; ++j) {
        const int rowg = m0 + wm * 64 + m * 16 + g * 4 + j;
        float v = acc[m][n][j] + bias;
        if constexpr (MODE == 0) {
          const int b_ = rowg >> 12, sl = rowg & 4095;
          const size_t bh = (size_t)(b_ * 8 + h);
          if (mat == 0)      oq[(bh * 4096 + sl) * 64 + d] = f2b(v * ATT_SCALE);
          else if (mat == 1) ok[(bh * 4096 + sl) * 64 + d] = f2b(v);
          else               ov[(bh * 64 + d) * 4096 + sl] = f2b(v);
        } else {
          fo[(size_t)rowg * 512 + n0 + d] = v;
        }
      }
    }
  }
}

// ---------------- flash attention ----------------
// grid (S/64, B*H); 4 waves x 16 q-rows; KV tiles of 64 keys, double-buffered.
__global__ __launch_bounds__(256, 2) void k_attn(
    const short* __restrict__ Q, const short* __restrict__ K,
    const short* __restrict__ Vt, const int* __restrict__ mask,
    short* __restrict__ out) {
  __shared__ short Ksm[2][64 * 64];
  __shared__ short Vsm[2][64 * 64];
  __shared__ int Mism[2][64];
  __shared__ short Psm[4][16 * 72];  // per-wave P, row stride 72 elems (2-way banks)

  const int tid = threadIdx.x;
  const int wave = tid >> 6, lane = tid & 63;
  const int lane15 = lane & 15, g = lane >> 4;
  const int bh = blockIdx.y, b = bh >> 3, h = bh & 7;
  const int qt = blockIdx.x;

  const char* Kg = (const char*)K + (size_t)bh * 4096 * 128;  // [key][64] bf16
  const char* Vg = (const char*)Vt + (size_t)bh * 64 * 8192;  // [d][4096] bf16
  const short* Qg = Q + (size_t)bh * 4096 * 64;
  const int* mg = mask + b * 4096;

  const int qrow = qt * 64 + wave * 16 + lane15;
  const bf16x8 aq0 = *(const bf16x8*)(Qg + (size_t)qrow * 64 + g * 8);
  const bf16x8 aq1 = *(const bf16x8*)(Qg + (size_t)qrow * 64 + 32 + g * 8);

  auto stage = [&](int buf, int t) {
#pragma unroll
    for (int q = 0; q < 2; ++q) {
      int s_ = (wave * 2 + q) * 64 + lane;
      int row = s_ >> 3, ch = s_ & 7;
      gload_lds16(Kg + (size_t)t * 8192 + row * 128 + (((ch ^ row) & 7) << 4),
                  (char*)&Ksm[buf][0] + s_ * 16);
      gload_lds16(Vg + (size_t)row * 8192 + t * 128 + (((ch ^ row) & 7) << 4),
                  (char*)&Vsm[buf][0] + s_ * 16);
    }
    if (wave == 0) gload_lds4(mg + t * 64 + lane, &Mism[buf][lane]);
  };

  f32x4 O[4] = {};
  float m_[4] = {-1e30f, -1e30f, -1e30f, -1e30f};
  float l_[4] = {0.f, 0.f, 0.f, 0.f};

  stage(0, 0);
  asm volatile("s_waitcnt vmcnt(0)" ::: "memory");
  __syncthreads();

  for (int t = 0; t < 64; ++t) {
    const int cur = t & 1;
    if (t < 63) stage(cur ^ 1, t + 1);

    // ---- scores: S[q][key] for 64 keys (4 n-tiles of 16) ----
    f32x4 sf[4];
#pragma unroll
    for (int nt = 0; nt < 4; ++nt) {
      bf16x8 k0 = lds_read_swz(&Ksm[cur][0], nt * 16 + lane15, g);
      bf16x8 k1 = lds_read_swz(&Ksm[cur][0], nt * 16 + lane15, 4 + g);
      f32x4 z = {0.f, 0.f, 0.f, 0.f};
      z = MFMA16(aq0, k0, z);
      z = MFMA16(aq1, k1, z);
      const float ma = (Mism[cur][nt * 16 + lane15] == 1) ? -1.0e9f : 0.0f;
      const f32x4 mv = {ma, ma, ma, ma};
      sf[nt] = z + mv;
    }

    // ---- online softmax (row r = g*4+j owned by 16-lane group g) ----
    float sc[4];
#pragma unroll
    for (int j = 0; j < 4; ++j) {
      float v = fmaxf(fmaxf(sf[0][j], sf[1][j]), fmaxf(sf[2][j], sf[3][j]));
      v = fmaxf(v, __shfl_xor(v, 1));
      v = fmaxf(v, __shfl_xor(v, 2));
      v = fmaxf(v, __shfl_xor(v, 4));
      v = fmaxf(v, __shfl_xor(v, 8));
      const float nm = fmaxf(m_[j], v);
      sc[j] = __expf(m_[j] - nm);
      m_[j] = nm;
    }
    const f32x4 scv = {sc[0], sc[1], sc[2], sc[3]};
#pragma unroll
    for (int nt = 0; nt < 4; ++nt) O[nt] *= scv;

    float ls[4] = {0.f, 0.f, 0.f, 0.f};
#pragma unroll
    for (int nt = 0; nt < 4; ++nt) {
#pragma unroll
      for (int j = 0; j < 4; ++j) {
        const float p = __expf(sf[nt][j] - m_[j]);
        ls[j] += p;
        Psm[wave][(g * 4 + j) * 72 + nt * 16 + lane15] = f2b(p);
      }
    }
#pragma unroll
    for (int j = 0; j < 4; ++j) {
      float v = ls[j];
      v += __shfl_xor(v, 1);
      v += __shfl_xor(v, 2);
      v += __shfl_xor(v, 4);
      v += __shfl_xor(v, 8);
      l_[j] = l_[j] * sc[j] + v;
    }

    // ---- O += P @ V ----
    const bf16x8 pa0 = *(const bf16x8*)(&Psm[wave][lane15 * 72 + g * 8]);
    const bf16x8 pa1 = *(const bf16x8*)(&Psm[wave][lane15 * 72 + 32 + g * 8]);
#pragma unroll
    for (int nt = 0; nt < 4; ++nt) {
      bf16x8 v0 = lds_read_swz(&Vsm[cur][0], nt * 16 + lane15, g);
      bf16x8 v1 = lds_read_swz(&Vsm[cur][0], nt * 16 + lane15, 4 + g);
      O[nt] = MFMA16(pa0, v0, O[nt]);
      O[nt] = MFMA16(pa1, v1, O[nt]);
    }

    asm volatile("s_waitcnt vmcnt(0)" ::: "memory");
    __syncthreads();
  }

  float inv[4];
#pragma unroll
  for (int j = 0; j < 4; ++j) inv[j] = 1.0f / l_[j];

  short* og = out + (size_t)(b * 4096 + qt * 64 + wave * 16) * 512 + h * 64;
#pragma unroll
  for (int nt = 0; nt < 4; ++nt)
#pragma unroll
    for (int j = 0; j < 4; ++j)
      og[(size_t)(g * 4 + j) * 512 + nt * 16 + lane15] = f2b(O[nt][j] * inv[j]);
}

// ---------------- launch ----------------
extern "C" void kernel_launch(void* const* d_in, const int* in_sizes, int n_in,
                              void* d_out, int out_size, void* d_ws, size_t ws_size,
                              hipStream_t stream) {
  const float* x  = (const float*)d_in[0];
  const int* mask = (const int*)d_in[1];
  const float* Wq = (const float*)d_in[2];
  const float* bq = (const float*)d_in[3];
  const float* Wk = (const float*)d_in[4];
  const float* bk = (const float*)d_in[5];
  const float* Wv = (const float*)d_in[6];
  const float* bv = (const float*)d_in[7];
  const float* Wo = (const float*)d_in[8];
  const float* bo = (const float*)d_in[9];
  float* out = (float*)d_out;

  short* xb   = (short*)d_ws;                  // 8192*512 bf16
  short* wt   = xb + (size_t)8192 * 512;       // 4*512*512 bf16 (transposed weights)
  short* qws  = wt + (size_t)4 * 512 * 512;    // [bh][s][d], pre-scaled
  short* kws  = qws + (size_t)8192 * 512;      // [bh][s][d]
  short* vws  = kws + (size_t)8192 * 512;      // [bh][d][s]
  short* aout = vws + (size_t)8192 * 512;      // [b*s][512] bf16

  k_cvt_x<<<4096, 256, 0, stream>>>(x, xb);
  k_cvt_w<<<4096, 256, 0, stream>>>(Wq, Wk, Wv, Wo, wt);
  k_gemm<0><<<dim3(64, 24), 256, 0, stream>>>(xb, wt, bq, bk, bv, qws, kws, vws, nullptr);
  k_attn<<<dim3(64, 16), 256, 0, stream>>>(qws, kws, vws, mask, aout);
  k_gemm<1><<<dim3(64, 8), 256, 0, stream>>>(aout, wt + (size_t)3 * 512 * 512, bo, nullptr,
                                             nullptr, nullptr, nullptr, nullptr, out);
}

// Round 2
// 226.925 us; speedup vs baseline: 1.6035x; 1.6035x over previous
//
#include <hip/hip_runtime.h>
#include <hip/hip_bf16.h>
#include <stdint.h>

typedef __attribute__((ext_vector_type(8))) short bf16x8;
typedef __attribute__((ext_vector_type(4))) float f32x4;
typedef __attribute__((ext_vector_type(16))) float f32x16;
typedef __attribute__((ext_vector_type(4))) unsigned int u32x4;

#define MFMA16(a, b, c) __builtin_amdgcn_mfma_f32_16x16x32_bf16(a, b, c, 0, 0, 0)
#define MFMA32(a, b, c) __builtin_amdgcn_mfma_f32_32x32x16_bf16(a, b, c, 0, 0, 0)

constexpr float ATT_SCALE = 0.04419417382415922f;            // 1/sqrt(512)
constexpr float QSCALE = 0.04419417382415922f * 1.4426950408889634f;  // *log2(e)

__device__ __forceinline__ void gload_lds16(const void* g, void* l) {
  __builtin_amdgcn_global_load_lds((const __attribute__((address_space(1))) uint32_t*)g,
                                   (__attribute__((address_space(3))) uint32_t*)l, 16, 0, 0);
}
__device__ __forceinline__ void gload_lds4(const void* g, void* l) {
  __builtin_amdgcn_global_load_lds((const __attribute__((address_space(1))) uint32_t*)g,
                                   (__attribute__((address_space(3))) uint32_t*)l, 4, 0, 0);
}
// read 8 bf16 (16B) at logical (row, 16B-chunk ch) of a row-major [R][64]bf16 tile,
// stored with source-side XOR swizzle: slot(row, c) holds element chunk (c^(row&7))
__device__ __forceinline__ bf16x8 lds_read_swz(const short* base, int row, int ch) {
  return *(const bf16x8*)((const char*)base + row * 128 + (((ch ^ row) & 7) << 4));
}
__device__ __forceinline__ short f2b(float f) {
  __hip_bfloat16 h = __float2bfloat16(f);
  return *reinterpret_cast<short*>(&h);
}
__device__ __forceinline__ float exp2fast(float x) {
#if __has_builtin(__builtin_amdgcn_exp2f)
  return __builtin_amdgcn_exp2f(x);
#else
  return exp2f(x);
#endif
}

// ---------------- converters ----------------
__global__ void k_cvt_x(const float* __restrict__ x, short* __restrict__ xb) {
  const int i = blockIdx.x * 256 + threadIdx.x;
  const float4 v = ((const float4*)x)[i];
  short4 o;
  o.x = f2b(v.x); o.y = f2b(v.y); o.z = f2b(v.z); o.w = f2b(v.w);
  ((short4*)xb)[i] = o;
}

// wt[mat][n][k] = bf16(W_mat[k][n]) ; mat: 0=Wq 1=Wk 2=Wv 3=Wo
__global__ void k_cvt_w(const float* __restrict__ wq, const float* __restrict__ wk,
                        const float* __restrict__ wv, const float* __restrict__ wo,
                        short* __restrict__ wt) {
  const int gid = blockIdx.x * 256 + threadIdx.x;
  const int mat = gid >> 18;
  const int idx = gid & 262143;
  const int n = idx >> 9, k = idx & 511;
  const float* w = (mat == 0) ? wq : (mat == 1) ? wk : (mat == 2) ? wv : wo;
  wt[gid] = f2b(w[k * 512 + n]);
}

__global__ void k_cvt_m(const int* __restrict__ m, float* __restrict__ mf) {
  const int i = blockIdx.x * 256 + threadIdx.x;  // 8192
  mf[i] = (m[i] == 1) ? -1.0e9f : 0.0f;
}

// ---------------- GEMM: C[M x 64-block] = A[M x 512] * W^T-block + bias ----------------
// MODE 0: A = x_bf16, blockIdx.y in [0,24): mat=y>>3 (Q/K/V), head h=y&7.
//   Q -> qws[bh][s][d] * QSCALE ; K -> kws[bh][s][d] ;
//   V -> vws[bh][d][s'] transposed with quad-permuted key order (s' = quad-bitswap(s))
// MODE 1: A = attn_out bf16, W = Wo^T, f32 out[rows][512]
template <int MODE>
__global__ __launch_bounds__(256, 2) void k_gemm(
    const short* __restrict__ A, const short* __restrict__ W,
    const float* __restrict__ bias0, const float* __restrict__ bias1,
    const float* __restrict__ bias2,
    short* __restrict__ oq, short* __restrict__ ok, short* __restrict__ ov,
    float* __restrict__ fo) {
  __shared__ short Asm[2][128 * 64];
  __shared__ short Bsm[2][64 * 64];
  const int tid = threadIdx.x;
  const int wave = tid >> 6, lane = tid & 63;
  const int lane15 = lane & 15, g = lane >> 4;
  const int wm = wave >> 1, wn = wave & 1;
  const int m0 = blockIdx.x * 128;

  int mat = 0, n0, h = 0;
  const float* bptr;
  if constexpr (MODE == 0) {
    mat = blockIdx.y >> 3; h = blockIdx.y & 7; n0 = h * 64;
    bptr = (mat == 0) ? bias0 : (mat == 1) ? bias1 : bias2;
  } else {
    n0 = blockIdx.y * 64; bptr = bias0;
  }
  const char* Ag = (const char*)A + (size_t)m0 * 1024;
  const char* Bg = (const char*)(W + (size_t)mat * (512 * 512)) + (size_t)n0 * 1024;

  f32x4 acc[4][2] = {};

  auto stage = [&](int buf, int kt) {
    const int k0b = kt * 128;
#pragma unroll
    for (int q = 0; q < 4; ++q) {
      int s_ = (wave * 4 + q) * 64 + lane;
      int row = s_ >> 3, ch = s_ & 7;
      gload_lds16(Ag + (size_t)row * 1024 + k0b + (((ch ^ row) & 7) << 4),
                  (char*)&Asm[buf][0] + s_ * 16);
    }
#pragma unroll
    for (int q = 0; q < 2; ++q) {
      int s_ = (wave * 2 + q) * 64 + lane;
      int row = s_ >> 3, ch = s_ & 7;
      gload_lds16(Bg + (size_t)row * 1024 + k0b + (((ch ^ row) & 7) << 4),
                  (char*)&Bsm[buf][0] + s_ * 16);
    }
  };

  stage(0, 0);
  asm volatile("s_waitcnt vmcnt(0)" ::: "memory");
  __syncthreads();

  for (int kt = 0; kt < 8; ++kt) {
    const int cur = kt & 1;
    if (kt < 7) stage(cur ^ 1, kt + 1);
#pragma unroll
    for (int kk = 0; kk < 2; ++kk) {
      bf16x8 af[4], bfr[2];
#pragma unroll
      for (int m = 0; m < 4; ++m)
        af[m] = lds_read_swz(&Asm[cur][0], wm * 64 + m * 16 + lane15, kk * 4 + g);
#pragma unroll
      for (int n = 0; n < 2; ++n)
        bfr[n] = lds_read_swz(&Bsm[cur][0], wn * 32 + n * 16 + lane15, kk * 4 + g);
#pragma unroll
      for (int m = 0; m < 4; ++m)
#pragma unroll
        for (int n = 0; n < 2; ++n)
          acc[m][n] = MFMA16(af[m], bfr[n], acc[m][n]);
    }
    asm volatile("s_waitcnt vmcnt(0)" ::: "memory");
    __syncthreads();
  }

#pragma unroll
  for (int n = 0; n < 2; ++n) {
    const int d = wn * 32 + n * 16 + lane15;
    const float bias = bptr[n0 + d];
#pragma unroll
    for (int m = 0; m < 4; ++m) {
#pragma unroll
      for (int j = 0; j < 4; ++j) {
        const int rowg = m0 + wm * 64 + m * 16 + g * 4 + j;
        float v = acc[m][n][j] + bias;
        if constexpr (MODE == 0) {
          const int b_ = rowg >> 12, sl = rowg & 4095;
          const size_t bh = (size_t)(b_ * 8 + h);
          if (mat == 0)      oq[(bh * 4096 + sl) * 64 + d] = f2b(v * QSCALE);
          else if (mat == 1) ok[(bh * 4096 + sl) * 64 + d] = f2b(v);
          else {
            // quad-permute key position within each 16-key group: quad 1<->2
            const int lq = (sl >> 2) & 3;
            const int lqp = ((lq & 1) << 1) | (lq >> 1);
            const int slp = (sl & ~12) | (lqp << 2);
            ov[(bh * 64 + d) * 4096 + slp] = f2b(v);
          }
        } else {
          fo[(size_t)rowg * 512 + n0 + d] = v;
        }
      }
    }
  }
}

// ---------------- flash attention (swapped-operand 32x32) ----------------
// grid (S/128, B*H); 4 waves x 32 q-rows; KV tiles of 64 keys, double-buffered.
// QK^T computed as mfma(K, Q): score col = q = lane&31  -> softmax state per-lane.
// PV computed as mfma(V^T, P): O col = q               -> rescale per-lane scalar.
// V^T workspace is quad-permuted so P fragments are lane-local (no cross-lane ops).
__global__ __launch_bounds__(256, 2) void k_attn(
    const short* __restrict__ Q, const short* __restrict__ K,
    const short* __restrict__ Vt, const float* __restrict__ maskf,
    short* __restrict__ out) {
  __shared__ short Ksm[2][64 * 64];
  __shared__ short Vsm[2][64 * 64];
  __shared__ float Msm[2][64];

  const int tid = threadIdx.x;
  const int wave = tid >> 6, lane = tid & 63;
  const int l31 = lane & 31, h = lane >> 5;
  const int bh = blockIdx.y, b = bh >> 3, hh = bh & 7;
  const int q0 = blockIdx.x * 128 + wave * 32;

  const char* Kg = (const char*)K + (size_t)bh * 4096 * 128;   // [key][64] bf16
  const char* Vg = (const char*)Vt + (size_t)bh * 64 * 8192;   // [d][4096] bf16 (perm'd)
  const float* mg = maskf + b * 4096;

  // Q fragment: B-operand of mfma(K,Q): col=q=l31, k-elems = dk*16 + 8h + 0..7
  const short* Qrow = Q + (size_t)bh * 4096 * 64 + (size_t)(q0 + l31) * 64;
  bf16x8 qreg[4];
#pragma unroll
  for (int dk = 0; dk < 4; ++dk) qreg[dk] = *(const bf16x8*)(Qrow + (2 * dk + h) * 8);

  auto stage = [&](int buf, int tt) {
#pragma unroll
    for (int qq = 0; qq < 2; ++qq) {
      int s_ = (wave * 2 + qq) * 64 + lane;
      int row = s_ >> 3, ch = s_ & 7;
      gload_lds16(Kg + (size_t)tt * 8192 + row * 128 + (((ch ^ row) & 7) << 4),
                  (char*)&Ksm[buf][0] + s_ * 16);
      gload_lds16(Vg + (size_t)row * 8192 + (size_t)tt * 128 + (((ch ^ row) & 7) << 4),
                  (char*)&Vsm[buf][0] + s_ * 16);
    }
    if (wave == 0) gload_lds4(mg + tt * 64 + lane, &Msm[buf][lane]);
  };

  f32x16 o0 = {}, o1 = {};
  float m_ = -1.0e30f, l_ = 0.f;

  stage(0, 0);
  asm volatile("s_waitcnt vmcnt(0)" ::: "memory");
  __syncthreads();

  for (int t = 0; t < 64; ++t) {
    const int cur = t & 1;
    if (t < 63) stage(cur ^ 1, t + 1);

    // score accumulators initialized with mask addend (per-row = per-key)
    union SU { f32x16 v; f32x4 q[4]; } su0, su1;
#pragma unroll
    for (int r2 = 0; r2 < 4; ++r2) {
      su0.q[r2] = *(const f32x4*)&Msm[cur][0 + 8 * r2 + 4 * h];
      su1.q[r2] = *(const f32x4*)&Msm[cur][32 + 8 * r2 + 4 * h];
    }
    f32x16 s0v = su0.v, s1v = su1.v;

    __builtin_amdgcn_s_setprio(1);
#pragma unroll
    for (int dk = 0; dk < 4; ++dk) {
      bf16x8 k0 = lds_read_swz(&Ksm[cur][0], l31, 2 * dk + h);
      bf16x8 k1 = lds_read_swz(&Ksm[cur][0], 32 + l31, 2 * dk + h);
      s0v = MFMA32(k0, qreg[dk], s0v);
      s1v = MFMA32(k1, qreg[dk], s1v);
    }
    __builtin_amdgcn_s_setprio(0);

    // per-lane row max over all 64 keys (halves exchange via xor-32)
    float pm = s0v[0];
#pragma unroll
    for (int i = 1; i < 16; ++i) pm = fmaxf(pm, s0v[i]);
#pragma unroll
    for (int i = 0; i < 16; ++i) pm = fmaxf(pm, s1v[i]);
    pm = fmaxf(pm, __shfl_xor(pm, 32));

    if (__any(pm > m_ + 8.f)) {   // defer-max: rescale only when needed
      const float nm = fmaxf(m_, pm);
      const float sc = exp2fast(m_ - nm);
      m_ = nm;
      l_ *= sc;
      o0 = o0 * sc;
      o1 = o1 * sc;
    }

    unsigned int wA[8], wB[8];
    float ts = 0.f;
#pragma unroll
    for (int j2 = 0; j2 < 8; ++j2) {
      float a0 = exp2fast(s0v[2 * j2] - m_);
      float a1 = exp2fast(s0v[2 * j2 + 1] - m_);
      float b0 = exp2fast(s1v[2 * j2] - m_);
      float b1 = exp2fast(s1v[2 * j2 + 1] - m_);
      ts += (a0 + a1) + (b0 + b1);
      asm("v_cvt_pk_bf16_f32 %0, %1, %2" : "=v"(wA[j2]) : "v"(a0), "v"(a1));
      asm("v_cvt_pk_bf16_f32 %0, %1, %2" : "=v"(wB[j2]) : "v"(b0), "v"(b1));
    }
    ts += __shfl_xor(ts, 32);
    l_ += ts;

    __builtin_amdgcn_s_setprio(1);
#pragma unroll
    for (int s = 0; s < 4; ++s) {
      const unsigned int* w = (s < 2) ? wA : wB;
      union PU { u32x4 u; bf16x8 f; } pu;
      pu.u[0] = w[4 * (s & 1) + 0];
      pu.u[1] = w[4 * (s & 1) + 1];
      pu.u[2] = w[4 * (s & 1) + 2];
      pu.u[3] = w[4 * (s & 1) + 3];
      bf16x8 v0 = lds_read_swz(&Vsm[cur][0], l31, 2 * s + h);
      bf16x8 v1 = lds_read_swz(&Vsm[cur][0], 32 + l31, 2 * s + h);
      o0 = MFMA32(v0, pu.f, o0);
      o1 = MFMA32(v1, pu.f, o1);
    }
    __builtin_amdgcn_s_setprio(0);

    asm volatile("s_waitcnt vmcnt(0)" ::: "memory");
    __syncthreads();
  }

  const float inv = 1.0f / l_;
  short* og = out + (size_t)(b * 4096 + q0 + l31) * 512 + hh * 64;
#pragma unroll
  for (int r2 = 0; r2 < 4; ++r2) {
    {
      const int base = 8 * r2 + 4 * h;
      short4 s4;
      s4.x = f2b(o0[4 * r2 + 0] * inv);
      s4.y = f2b(o0[4 * r2 + 1] * inv);
      s4.z = f2b(o0[4 * r2 + 2] * inv);
      s4.w = f2b(o0[4 * r2 + 3] * inv);
      *(short4*)(og + base) = s4;
    }
    {
      const int base = 32 + 8 * r2 + 4 * h;
      short4 s4;
      s4.x = f2b(o1[4 * r2 + 0] * inv);
      s4.y = f2b(o1[4 * r2 + 1] * inv);
      s4.z = f2b(o1[4 * r2 + 2] * inv);
      s4.w = f2b(o1[4 * r2 + 3] * inv);
      *(short4*)(og + base) = s4;
    }
  }
}

// ---------------- launch ----------------
extern "C" void kernel_launch(void* const* d_in, const int* in_sizes, int n_in,
                              void* d_out, int out_size, void* d_ws, size_t ws_size,
                              hipStream_t stream) {
  const float* x  = (const float*)d_in[0];
  const int* mask = (const int*)d_in[1];
  const float* Wq = (const float*)d_in[2];
  const float* bq = (const float*)d_in[3];
  const float* Wk = (const float*)d_in[4];
  const float* bk = (const float*)d_in[5];
  const float* Wv = (const float*)d_in[6];
  const float* bv = (const float*)d_in[7];
  const float* Wo = (const float*)d_in[8];
  const float* bo = (const float*)d_in[9];
  float* out = (float*)d_out;

  short* xb   = (short*)d_ws;                  // 8192*512 bf16
  short* wt   = xb + (size_t)8192 * 512;       // 4*512*512 bf16 (transposed weights)
  short* qws  = wt + (size_t)4 * 512 * 512;    // [bh][s][d], pre-scaled by QSCALE
  short* kws  = qws + (size_t)8192 * 512;      // [bh][s][d]
  short* vws  = kws + (size_t)8192 * 512;      // [bh][d][s] quad-permuted
  short* aout = vws + (size_t)8192 * 512;      // [b*s][512] bf16
  float* mfws = (float*)(aout + (size_t)8192 * 512);  // [b][s] mask addend

  k_cvt_x<<<4096, 256, 0, stream>>>(x, xb);
  k_cvt_w<<<4096, 256, 0, stream>>>(Wq, Wk, Wv, Wo, wt);
  k_cvt_m<<<32, 256, 0, stream>>>(mask, mfws);
  k_gemm<0><<<dim3(64, 24), 256, 0, stream>>>(xb, wt, bq, bk, bv, qws, kws, vws, nullptr);
  k_attn<<<dim3(32, 16), 256, 0, stream>>>(qws, kws, vws, mfws, aout);
  k_gemm<1><<<dim3(64, 8), 256, 0, stream>>>(aout, wt + (size_t)3 * 512 * 512, bo, nullptr,
                                             nullptr, nullptr, nullptr, nullptr, out);
}

// Round 3
// 193.589 us; speedup vs baseline: 1.8796x; 1.1722x over previous
//
#include <hip/hip_runtime.h>
#include <hip/hip_bf16.h>
#include <stdint.h>

typedef __attribute__((ext_vector_type(8))) short bf16x8;
typedef __attribute__((ext_vector_type(4))) float f32x4;
typedef __attribute__((ext_vector_type(16))) float f32x16;
typedef __attribute__((ext_vector_type(4))) unsigned int u32x4;

#define MFMA16(a, b, c) __builtin_amdgcn_mfma_f32_16x16x32_bf16(a, b, c, 0, 0, 0)
#define MFMA32(a, b, c) __builtin_amdgcn_mfma_f32_32x32x16_bf16(a, b, c, 0, 0, 0)

constexpr float QSCALE = 0.04419417382415922f * 1.4426950408889634f;  // 1/sqrt(512) * log2(e)

__device__ __forceinline__ void gload_lds16(const void* g, void* l) {
  __builtin_amdgcn_global_load_lds((const __attribute__((address_space(1))) uint32_t*)g,
                                   (__attribute__((address_space(3))) uint32_t*)l, 16, 0, 0);
}
__device__ __forceinline__ bf16x8 lds_read_swz(const short* base, int row, int ch) {
  return *(const bf16x8*)((const char*)base + row * 128 + (((ch ^ row) & 7) << 4));
}
__device__ __forceinline__ short f2b(float f) {
  __hip_bfloat16 h = __float2bfloat16(f);
  return *reinterpret_cast<short*>(&h);
}
__device__ __forceinline__ float exp2fast(float x) {
#if __has_builtin(__builtin_amdgcn_exp2f)
  return __builtin_amdgcn_exp2f(x);
#else
  return exp2f(x);
#endif
}

// ---------------- converters ----------------
__global__ void k_cvt_x(const float* __restrict__ x, short* __restrict__ xb) {
  const int i = blockIdx.x * 256 + threadIdx.x;
  const float4 v = ((const float4*)x)[i];
  short4 o;
  o.x = f2b(v.x); o.y = f2b(v.y); o.z = f2b(v.z); o.w = f2b(v.w);
  ((short4*)xb)[i] = o;
}

// wt[mat][n][k] = bf16(W_mat[k][n]) ; mat: 0=Wq 1=Wk 2=Wv 3=Wo
__global__ void k_cvt_w(const float* __restrict__ wq, const float* __restrict__ wk,
                        const float* __restrict__ wv, const float* __restrict__ wo,
                        short* __restrict__ wt) {
  const int gid = blockIdx.x * 256 + threadIdx.x;
  const int mat = gid >> 18;
  const int idx = gid & 262143;
  const int n = idx >> 9, k = idx & 511;
  const float* w = (mat == 0) ? wq : (mat == 1) ? wk : (mat == 2) ? wv : wo;
  wt[gid] = f2b(w[k * 512 + n]);
}

// ---------------- prefix-scan of kept keys (mask==0) ----------------
// perm[b][s] = compact position (or -1 if masked) ; cnt[b] = #kept
__global__ void k_scan(const int* __restrict__ mask, int* __restrict__ perm,
                       int* __restrict__ cnt) {
  __shared__ int ws[16];
  const int b = blockIdx.x, tid = threadIdx.x;  // 1024 threads
  const int lane = tid & 63, w = tid >> 6;
  const int* m = mask + b * 4096;
  int v[4], s = 0;
#pragma unroll
  for (int j = 0; j < 4; ++j) { v[j] = (m[tid * 4 + j] == 0) ? 1 : 0; s += v[j]; }
  int sc = s;
  for (int d = 1; d < 64; d <<= 1) { int t = __shfl_up(sc, d); if (lane >= d) sc += t; }
  if (lane == 63) ws[w] = sc;
  __syncthreads();
  if (tid == 0) {
    int acc = 0;
    for (int i = 0; i < 16; ++i) { int t = ws[i]; ws[i] = acc; acc += t; }
    cnt[b] = acc;
  }
  __syncthreads();
  int pos = ws[w] + sc - s;
  int* p = perm + b * 4096;
#pragma unroll
  for (int j = 0; j < 4; ++j) { p[tid * 4 + j] = v[j] ? pos : -1; pos += v[j]; }
}

// ---------------- GEMM: C[M x 64-block] = A[M x 512] * W^T-block + bias ----------------
// MODE 0: A = x_bf16, blockIdx.y in [0,24): mat=y>>3 (Q/K/V), head h=y&7.
//   Epilogues scatter into MFMA-fragment-ordered workspaces (see k_attn):
//   Q' (scaled by QSCALE), K' (compacted), V' (compacted + bits2/3-swapped key order).
// MODE 1: A = attn_out bf16, W = Wo^T, f32 out[rows][512]
template <int MODE>
__global__ __launch_bounds__(256, 2) void k_gemm(
    const short* __restrict__ A, const short* __restrict__ W,
    const float* __restrict__ bias0, const float* __restrict__ bias1,
    const float* __restrict__ bias2, const int* __restrict__ perm,
    short* __restrict__ oq, short* __restrict__ ok, short* __restrict__ ov,
    float* __restrict__ fo) {
  __shared__ short Asm[2][128 * 64];
  __shared__ short Bsm[2][64 * 64];
  const int tid = threadIdx.x;
  const int wave = tid >> 6, lane = tid & 63;
  const int lane15 = lane & 15, g = lane >> 4;
  const int wm = wave >> 1, wn = wave & 1;
  const int m0 = blockIdx.x * 128;

  int mat = 0, n0, h = 0;
  const float* bptr;
  if constexpr (MODE == 0) {
    mat = blockIdx.y >> 3; h = blockIdx.y & 7; n0 = h * 64;
    bptr = (mat == 0) ? bias0 : (mat == 1) ? bias1 : bias2;
  } else {
    n0 = blockIdx.y * 64; bptr = bias0;
  }
  const char* Ag = (const char*)A + (size_t)m0 * 1024;
  const char* Bg = (const char*)(W + (size_t)mat * (512 * 512)) + (size_t)n0 * 1024;

  f32x4 acc[4][2] = {};

  auto stage = [&](int buf, int kt) {
    const int k0b = kt * 128;
#pragma unroll
    for (int q = 0; q < 4; ++q) {
      int s_ = (wave * 4 + q) * 64 + lane;
      int row = s_ >> 3, ch = s_ & 7;
      gload_lds16(Ag + (size_t)row * 1024 + k0b + (((ch ^ row) & 7) << 4),
                  (char*)&Asm[buf][0] + s_ * 16);
    }
#pragma unroll
    for (int q = 0; q < 2; ++q) {
      int s_ = (wave * 2 + q) * 64 + lane;
      int row = s_ >> 3, ch = s_ & 7;
      gload_lds16(Bg + (size_t)row * 1024 + k0b + (((ch ^ row) & 7) << 4),
                  (char*)&Bsm[buf][0] + s_ * 16);
    }
  };

  stage(0, 0);
  asm volatile("s_waitcnt vmcnt(0)" ::: "memory");
  __syncthreads();

  for (int kt = 0; kt < 8; ++kt) {
    const int cur = kt & 1;
    if (kt < 7) stage(cur ^ 1, kt + 1);
#pragma unroll
    for (int kk = 0; kk < 2; ++kk) {
      bf16x8 af[4], bfr[2];
#pragma unroll
      for (int m = 0; m < 4; ++m)
        af[m] = lds_read_swz(&Asm[cur][0], wm * 64 + m * 16 + lane15, kk * 4 + g);
#pragma unroll
      for (int n = 0; n < 2; ++n)
        bfr[n] = lds_read_swz(&Bsm[cur][0], wn * 32 + n * 16 + lane15, kk * 4 + g);
#pragma unroll
      for (int m = 0; m < 4; ++m)
#pragma unroll
        for (int n = 0; n < 2; ++n)
          acc[m][n] = MFMA16(af[m], bfr[n], acc[m][n]);
    }
    asm volatile("s_waitcnt vmcnt(0)" ::: "memory");
    __syncthreads();
  }

#pragma unroll
  for (int n = 0; n < 2; ++n) {
    const int d = wn * 32 + n * 16 + lane15;
    const float bias = bptr[n0 + d];
#pragma unroll
    for (int m = 0; m < 4; ++m) {
#pragma unroll
      for (int j = 0; j < 4; ++j) {
        const int rowg = m0 + wm * 64 + m * 16 + g * 4 + j;
        float v = acc[m][n][j] + bias;
        if constexpr (MODE == 0) {
          const int b_ = rowg >> 12, sl = rowg & 4095;
          const size_t bh = (size_t)(b_ * 8 + h);
          if (mat == 0) {
            const int qt32 = sl >> 5, l31q = sl & 31;
            const int dk = d >> 4, hb = (d >> 3) & 1, jj = d & 7;
            oq[bh * 262144 + (size_t)((qt32 * 4 + dk) * 64 + hb * 32 + l31q) * 8 + jj] =
                f2b(v * QSCALE);
          } else {
            const int pm = perm[b_ * 4096 + sl];
            if (pm >= 0) {
              const int t = pm >> 6, r = pm & 63;
              if (mat == 1) {
                const int x = r >> 5, l31k = r & 31;
                const int dk = d >> 4, hb = (d >> 3) & 1, jj = d & 7;
                ok[bh * 262144 + (size_t)((t * 8 + dk * 2 + x) * 64 + hb * 32 + l31k) * 8 + jj] =
                    f2b(v);
              } else {
                // storage index m = key with bits 2 and 3 swapped
                const int mm = (r & ~12) | (((r >> 2) & 1) << 3) | (((r >> 3) & 1) << 2);
                const int s = (mm >> 4) & 3, hb = (mm >> 3) & 1, jj = mm & 7;
                const int x = d >> 5, l31v = d & 31;
                ov[bh * 262144 + (size_t)((t * 8 + s * 2 + x) * 64 + hb * 32 + l31v) * 8 + jj] =
                    f2b(v);
              }
            }
          }
        } else {
          fo[(size_t)rowg * 512 + n0 + d] = v;
        }
      }
    }
  }
}

// ---------------- flash attention: no LDS, no barriers, direct L1/L2 reads ------------
// grid (32, 16); 4 independent waves/block, 32 q-rows each; KV tiles of 64 compacted keys.
// All operands pre-packed in fragment order: one coalesced dwordx4 load per fragment.
// QK^T = mfma(K, Q) -> score col = q = lane&31 (softmax per-lane).
// PV   = mfma(V', P) -> O col = q ; V' key order bit-swapped so P is lane-local.
#define ATT_BODY(T, KC, KN)                                                   \
  {                                                                           \
    bf16x8 v0_ = vld(T, 0), v1_ = vld(T, 1), v2_ = vld(T, 2), v3_ = vld(T, 3),\
           v4_ = vld(T, 4), v5_ = vld(T, 5), v6_ = vld(T, 6), v7_ = vld(T, 7);\
    f32x16 s0v = {}, s1v = {};                                                \
    __builtin_amdgcn_s_setprio(1);                                            \
    _Pragma("unroll") for (int dk = 0; dk < 4; ++dk) {                        \
      s0v = MFMA32(KC[2 * dk], qreg[dk], s0v);                                \
      s1v = MFMA32(KC[2 * dk + 1], qreg[dk], s1v);                            \
    }                                                                         \
    __builtin_amdgcn_s_setprio(0);                                            \
    _Pragma("unroll") for (int u = 0; u < 8; ++u) KN[u] = kld((T) + 1, u);    \
    if ((T) == nt - 1 && lim < 64) {                                          \
      _Pragma("unroll") for (int i = 0; i < 16; ++i) {                        \
        const int r0 = (i & 3) + 8 * (i >> 2) + 4 * h;                        \
        if (r0 >= lim) s0v[i] = -1e30f;                                       \
        if (r0 + 32 >= lim) s1v[i] = -1e30f;                                  \
      }                                                                       \
    }                                                                         \
    float pm = s0v[0];                                                        \
    _Pragma("unroll") for (int i = 1; i < 16; ++i) pm = fmaxf(pm, s0v[i]);    \
    _Pragma("unroll") for (int i = 0; i < 16; ++i) pm = fmaxf(pm, s1v[i]);    \
    pm = fmaxf(pm, __shfl_xor(pm, 32));                                       \
    if (__any(pm > m_ + 8.f)) {                                               \
      const float nm = fmaxf(m_, pm);                                         \
      const float sc = exp2fast(m_ - nm);                                     \
      m_ = nm; l_ *= sc; o0 = o0 * sc; o1 = o1 * sc;                          \
    }                                                                         \
    unsigned int wA[8], wB[8];                                                \
    float ts = 0.f;                                                           \
    _Pragma("unroll") for (int j2 = 0; j2 < 8; ++j2) {                        \
      float a0 = exp2fast(s0v[2 * j2] - m_);                                  \
      float a1 = exp2fast(s0v[2 * j2 + 1] - m_);                              \
      float b0 = exp2fast(s1v[2 * j2] - m_);                                  \
      float b1 = exp2fast(s1v[2 * j2 + 1] - m_);                              \
      ts += (a0 + a1) + (b0 + b1);                                            \
      asm("v_cvt_pk_bf16_f32 %0, %1, %2" : "=v"(wA[j2]) : "v"(a0), "v"(a1));  \
      asm("v_cvt_pk_bf16_f32 %0, %1, %2" : "=v"(wB[j2]) : "v"(b0), "v"(b1));  \
    }                                                                         \
    ts += __shfl_xor(ts, 32);                                                 \
    l_ += ts;                                                                 \
    __builtin_amdgcn_s_setprio(1);                                            \
    {                                                                         \
      union PU { u32x4 u; bf16x8 f; } pu;                                     \
      pu.u[0] = wA[0]; pu.u[1] = wA[1]; pu.u[2] = wA[2]; pu.u[3] = wA[3];     \
      o0 = MFMA32(v0_, pu.f, o0); o1 = MFMA32(v1_, pu.f, o1);                 \
      pu.u[0] = wA[4]; pu.u[1] = wA[5]; pu.u[2] = wA[6]; pu.u[3] = wA[7];     \
      o0 = MFMA32(v2_, pu.f, o0); o1 = MFMA32(v3_, pu.f, o1);                 \
      pu.u[0] = wB[0]; pu.u[1] = wB[1]; pu.u[2] = wB[2]; pu.u[3] = wB[3];     \
      o0 = MFMA32(v4_, pu.f, o0); o1 = MFMA32(v5_, pu.f, o1);                 \
      pu.u[0] = wB[4]; pu.u[1] = wB[5]; pu.u[2] = wB[6]; pu.u[3] = wB[7];     \
      o0 = MFMA32(v6_, pu.f, o0); o1 = MFMA32(v7_, pu.f, o1);                 \
    }                                                                         \
    __builtin_amdgcn_s_setprio(0);                                            \
  }

__global__ __launch_bounds__(256, 2) void k_attn(
    const short* __restrict__ Qp, const short* __restrict__ Kp,
    const short* __restrict__ Vp, const int* __restrict__ cnt,
    short* __restrict__ out) {
  const int tid = threadIdx.x;
  const int wave = tid >> 6, lane = tid & 63;
  const int l31 = lane & 31, h = lane >> 5;
  const int bh = blockIdx.y, b = bh >> 3, hh = bh & 7;
  const int qb = blockIdx.x * 4 + wave;  // 32-row q-block index

  const short* Qg = Qp + (size_t)bh * 262144;
  const short* Kg = Kp + (size_t)bh * 262144;
  const short* Vg = Vp + (size_t)bh * 262144;

  auto kld = [&](int t, int u) {
    return *(const bf16x8*)(Kg + ((size_t)(t * 8 + u) * 64 + lane) * 8);
  };
  auto vld = [&](int t, int u) {
    return *(const bf16x8*)(Vg + ((size_t)(t * 8 + u) * 64 + lane) * 8);
  };

  bf16x8 qreg[4];
#pragma unroll
  for (int dk = 0; dk < 4; ++dk)
    qreg[dk] = *(const bf16x8*)(Qg + ((size_t)(qb * 4 + dk) * 64 + lane) * 8);

  const int cn = cnt[b];
  const int nt = max(1, (cn + 63) >> 6);
  const int lim = cn - (nt - 1) * 64;  // keys in last tile (0..64)

  bf16x8 ka[8], kb[8];
#pragma unroll
  for (int u = 0; u < 8; ++u) ka[u] = kld(0, u);

  f32x16 o0 = {}, o1 = {};
  float m_ = -1.0e30f, l_ = 0.f;

  for (int t = 0; t < nt; t += 2) {
    ATT_BODY(t, ka, kb);
    if (t + 1 < nt) ATT_BODY(t + 1, kb, ka);
  }

  const float inv = 1.0f / l_;
  short* og = out + (size_t)(b * 4096 + qb * 32 + l31) * 512 + hh * 64;
#pragma unroll
  for (int r2 = 0; r2 < 4; ++r2) {
    {
      const int base = 8 * r2 + 4 * h;
      short4 s4;
      s4.x = f2b(o0[4 * r2 + 0] * inv);
      s4.y = f2b(o0[4 * r2 + 1] * inv);
      s4.z = f2b(o0[4 * r2 + 2] * inv);
      s4.w = f2b(o0[4 * r2 + 3] * inv);
      *(short4*)(og + base) = s4;
    }
    {
      const int base = 32 + 8 * r2 + 4 * h;
      short4 s4;
      s4.x = f2b(o1[4 * r2 + 0] * inv);
      s4.y = f2b(o1[4 * r2 + 1] * inv);
      s4.z = f2b(o1[4 * r2 + 2] * inv);
      s4.w = f2b(o1[4 * r2 + 3] * inv);
      *(short4*)(og + base) = s4;
    }
  }
}

// ---------------- launch ----------------
extern "C" void kernel_launch(void* const* d_in, const int* in_sizes, int n_in,
                              void* d_out, int out_size, void* d_ws, size_t ws_size,
                              hipStream_t stream) {
  const float* x  = (const float*)d_in[0];
  const int* mask = (const int*)d_in[1];
  const float* Wq = (const float*)d_in[2];
  const float* bq = (const float*)d_in[3];
  const float* Wk = (const float*)d_in[4];
  const float* bk = (const float*)d_in[5];
  const float* Wv = (const float*)d_in[6];
  const float* bv = (const float*)d_in[7];
  const float* Wo = (const float*)d_in[8];
  const float* bo = (const float*)d_in[9];
  float* out = (float*)d_out;

  short* xb   = (short*)d_ws;                  // 8192*512 bf16
  short* wt   = xb + (size_t)8192 * 512;       // 4*512*512 bf16 (transposed weights)
  short* qws  = wt + (size_t)4 * 512 * 512;    // Q' fragment-packed, QSCALE'd
  short* kws  = qws + (size_t)8192 * 512;      // K' fragment-packed, compacted
  short* vws  = kws + (size_t)8192 * 512;      // V' fragment-packed, compacted+bitswap
  short* aout = vws + (size_t)8192 * 512;      // [b*s][512] bf16
  int* perm   = (int*)(aout + (size_t)8192 * 512);  // [b][s]
  int* cntw   = perm + 8192;                   // [b]

  k_cvt_x<<<4096, 256, 0, stream>>>(x, xb);
  k_cvt_w<<<4096, 256, 0, stream>>>(Wq, Wk, Wv, Wo, wt);
  k_scan<<<2, 1024, 0, stream>>>(mask, perm, cntw);
  k_gemm<0><<<dim3(64, 24), 256, 0, stream>>>(xb, wt, bq, bk, bv, perm, qws, kws, vws, nullptr);
  k_attn<<<dim3(32, 16), 256, 0, stream>>>(qws, kws, vws, cntw, aout);
  k_gemm<1><<<dim3(64, 8), 256, 0, stream>>>(aout, wt + (size_t)3 * 512 * 512, bo, nullptr,
                                             nullptr, nullptr, nullptr, nullptr, nullptr, out);
}